// Round 12
// baseline (235.219 us; speedup 1.0000x reference)
//
#include <hip/hip_runtime.h>
#include <hip/hip_bf16.h>

#define D_MODEL 1024
#define N_HEADS 16
#define SEQ     2048
#define BATCH   4
#define CSC     (0.125f * 1.44269504f)   // (1/sqrt(dk)) * log2(e)

typedef __attribute__((ext_vector_type(8))) short short8;
typedef __attribute__((ext_vector_type(4))) float f32x4;

__device__ __forceinline__ ushort f2bf(float v) {
    __hip_bfloat16 b = __float2bfloat16(v);
    return __builtin_bit_cast(ushort, b);
}
__device__ __forceinline__ f32x4 mfma16(short8 a, short8 b, f32x4 c) {
    return __builtin_amdgcn_mfma_f32_16x16x32_bf16(a, b, c, 0, 0, 0);
}
// async global->LDS, 16B/lane. LDS base must be wave-uniform; global addr per-lane.
__device__ __forceinline__ void gload_lds16(const ushort* g, ushort* l) {
    __builtin_amdgcn_global_load_lds(
        (const __attribute__((address_space(1))) unsigned int*)g,
        (__attribute__((address_space(3))) unsigned int*)l, 16, 0, 0);
}

// ---------------------------------------------------------------------------
// fused prep: block-range dispatch.
//   blocks [0,2048):        x fp32 -> bf16 hi (grid-stride float4)
//   blocks [2048,5120):     W_attn transpose -> WaT [3072][1024] bf16
//                           (Q-cols n<1024 pre-scaled by CSC in fp32 — exact)
//   blocks [5120,6144):     W_proj transpose -> WpT [1024][1024] bf16
// ---------------------------------------------------------------------------
__global__ __launch_bounds__(256) void prep_k(const float* __restrict__ x,
                                              const float* __restrict__ Wa,
                                              const float* __restrict__ Wp,
                                              ushort* __restrict__ xh,
                                              ushort* __restrict__ WaT,
                                              ushort* __restrict__ WpT) {
    const int id = blockIdx.x;
    const int t = threadIdx.x;
    if (id < 2048) {
        const float4* x4 = (const float4*)x;
        ushort4* xh4 = (ushort4*)xh;
        const int n4 = BATCH * SEQ * D_MODEL / 4;
        for (int i = id * 256 + t; i < n4; i += 2048 * 256) {
            float4 v = x4[i];
            ushort4 hv;
            hv.x = f2bf(v.x);
            hv.y = f2bf(v.y);
            hv.z = f2bf(v.z);
            hv.w = f2bf(v.w);
            xh4[i] = hv;
        }
    } else {
        __shared__ float tile[32][33];
        const float* W;
        ushort* WT;
        int N, tid, scaleQ;
        if (id < 2048 + 3072) { tid = id - 2048; W = Wa; WT = WaT; N = 3072; scaleQ = 1; }
        else                  { tid = id - 5120; W = Wp; WT = WpT; N = 1024; scaleQ = 0; }
        const int nb = (tid % (N / 32)) * 32, kb = (tid / (N / 32)) * 32;
        const int tx = t & 31, ty = t >> 5;
#pragma unroll
        for (int i = 0; i < 4; ++i)
            tile[ty + 8 * i][tx] = W[(size_t)(kb + ty + 8 * i) * N + nb + tx];
        __syncthreads();
#pragma unroll
        for (int i = 0; i < 4; ++i) {
            int n = nb + ty + 8 * i;
            float v = tile[tx][ty + 8 * i];  // = W[kb+tx][n]
            if (scaleQ && n < 1024) v *= CSC;
            WT[(size_t)n * 1024 + kb + tx] = f2bf(v);
        }
    }
}

// ---------------------------------------------------------------------------
// bf16 MFMA GEMM, pipelined, 1-term (Ah*Bh): C[M,N] = A @ B
// A row-major [.,K] (lda, col offset aoff); B as B^T row-major [N][K].
// 128x128 tile, BK=32, 4 waves (2x2), 4x4 16x16 frags/wave.
// Cooperative staging, double-buffered LDS, counted vmcnt + raw s_barrier.
// VT_FUSE: blocks with col0 >= 2048 (the V columns of qkv) ALSO scatter the
// same bf16 bits into vT[(b*16+h)*64+d][s] — replaces the transpose kernel.
// ---------------------------------------------------------------------------
template <int OUT_SPLIT, int VT_FUSE>
__global__ __launch_bounds__(256) void gemm_k(
    const ushort* __restrict__ Ah, int lda, int aoff,
    const ushort* __restrict__ BhT,
    ushort* __restrict__ Ch, float* __restrict__ Cf, ushort* __restrict__ vT,
    int ldc, int coff, int K) {
    __shared__ __align__(16) ushort lds[2][2][4096];   // [buf][0=A,1=B]
    const int t = threadIdx.x;
    const int lane = t & 63, wid = t >> 6;
    const int wm = (wid >> 1) * 64, wn = (wid & 1) * 64;
    const int row0 = blockIdx.y * 128, col0 = blockIdx.x * 128;

    f32x4 acc[4][4];
#pragma unroll
    for (int i = 0; i < 4; ++i)
#pragma unroll
        for (int j = 0; j < 4; ++j) acc[i][j] = f32x4{0.f, 0.f, 0.f, 0.f};

    const int r_loc = lane >> 2;                       // 0..15
    const int c_src = (lane & 3) ^ ((lane >> 3) & 3);  // pre-swizzled source col
    const int swz = ((lane & 15) >> 1) & 3;
    const int ch = (((lane >> 4) ^ swz) * 8);
    const int rA = wm + (lane & 15);
    const int rB = wn + (lane & 15);

    // each wave stages 4 chunks (1KB each); chunk c -> tile c>>3, rows (c&7)*16+
    auto stage = [&](int buf, int kk) {
#pragma unroll
        for (int ic = 0; ic < 4; ++ic) {
            const int c = wid * 4 + ic;
            const int tile = c >> 3, chi = c & 7;
            const ushort* s = tile ? BhT : Ah;
            const int sr = tile ? col0 : row0;
            const int sl = tile ? K : lda;
            const int so = tile ? 0 : aoff;
            const ushort* gp =
                s + (size_t)(sr + chi * 16 + r_loc) * sl + so + kk + c_src * 8;
            gload_lds16(gp, &lds[buf][tile][chi * 512 + 0]);
        }
    };

    stage(0, 0);
    for (int k0 = 0; k0 < K; k0 += 32) {
        const int cur = (k0 >> 5) & 1;
        if (k0 + 32 < K) {
            stage(cur ^ 1, k0 + 32);   // prefetch next K-tile
            asm volatile("s_waitcnt vmcnt(4)" ::: "memory");
        } else {
            asm volatile("s_waitcnt vmcnt(0)" ::: "memory");
        }
        __builtin_amdgcn_s_barrier();      // cur buffer landed (all waves)
        __builtin_amdgcn_sched_barrier(0);

        short8 ah[4], bh[4];
#pragma unroll
        for (int f = 0; f < 4; ++f) {
            ah[f] = *(const short8*)&lds[cur][0][(rA + f * 16) * 32 + ch];
            bh[f] = *(const short8*)&lds[cur][1][(rB + f * 16) * 32 + ch];
        }
        __builtin_amdgcn_s_setprio(1);
#pragma unroll
        for (int i = 0; i < 4; ++i)
#pragma unroll
            for (int j = 0; j < 4; ++j) acc[i][j] = mfma16(ah[i], bh[j], acc[i][j]);
        __builtin_amdgcn_s_setprio(0);
        asm volatile("s_waitcnt lgkmcnt(0)" ::: "memory");  // reads of cur retired
        __builtin_amdgcn_s_barrier();
        __builtin_amdgcn_sched_barrier(0);
    }
    // epilogue; C/D layout: row=(lane>>4)*4+reg, col=lane&15
    const bool isV = VT_FUSE && (col0 >= 2048);   // block-uniform
#pragma unroll
    for (int i = 0; i < 4; ++i)
#pragma unroll
        for (int j = 0; j < 4; ++j)
#pragma unroll
            for (int r = 0; r < 4; ++r) {
                int row = row0 + wm + i * 16 + (lane >> 4) * 4 + r;
                int col = col0 + wn + j * 16 + (lane & 15);
                float v = acc[i][j][r];
                if (OUT_SPLIT) {
                    ushort hv = f2bf(v);
                    Ch[(size_t)row * ldc + coff + col] = hv;
                    if (isV) {
                        int hd = col - 2048;            // h*64+d
                        int bb = row >> 11, s = row & 2047;
                        vT[((size_t)(bb << 10) + hd) * SEQ + s] = hv;
                    }
                } else {
                    Cf[(size_t)row * ldc + coff + col] = v;
                }
            }
}

// ---------------------------------------------------------------------------
// MFMA flash attention (R10 version — known 120.5 us), pipelined, all bf16,
// 8 waves / QBLK=128. Q pre-scaled by CSC -> softmax = exp2(s) direct; no
// max-tracking; deferred l-reduction; kt-loop unrolled x2 (static buffer
// index). XCD-aware flat grid. K AND V double-buffered, counted vmcnt(2).
// ---------------------------------------------------------------------------
__global__ __launch_bounds__(512) void flash_mfma(
    const ushort* __restrict__ qkv_h, const ushort* __restrict__ vT_h,
    ushort* __restrict__ attn_h) {
    const int id = blockIdx.x;
    const int bh = id & 63, qt = id >> 6;
    const int h = bh & 15, b = bh >> 4;
    const int t = threadIdx.x, lane = t & 63, wid = t >> 6;  // wid 0..7
    const int q = lane & 15, g = lane >> 4;
    const int qs7 = q & 7;

    __shared__ __align__(16) ushort Kb[2][4096];   // 8 KB per buf (64x64)
    __shared__ __align__(16) ushort Vb[2][4096];
    __shared__ __align__(16) ushort Pb[8][1024];   // 2 KB per wave

    const size_t tokbase = (size_t)b * SEQ;
    const int q0 = qt * 128;
    const int kv_r = lane >> 3;
    const int kv_csrc = (lane & 7) ^ ((lane >> 3) & 7);
    const size_t vbase = ((size_t)(b * 16 + h) * 64) * SEQ;

    // ---- stage Q (128 rows) into Kb[0..1] (16 KB contiguous): 16 chunks
    ushort* KQ = &Kb[0][0];
#pragma unroll
    for (int is = 0; is < 2; ++is) {
        int ci = wid * 2 + is;
        const ushort* gq =
            qkv_h + (tokbase + q0 + ci * 8 + kv_r) * 3072 + h * 64 + kv_csrc * 8;
        gload_lds16(gq, KQ + ci * 512);
    }
    __syncthreads();  // drains vmcnt -> Q landed
    const int ck0 = (g ^ qs7) * 8;
    const int ck1 = ((g + 4) ^ qs7) * 8;
    short8 qh[2];
    {
        const int row = wid * 16 + q;
        qh[0] = *(const short8*)&KQ[row * 64 + ck0];
        qh[1] = *(const short8*)&KQ[row * 64 + ck1];
    }
    __syncthreads();  // frag reads retired before K overwrites

    // hoisted per-lane LDS offsets (kt-invariant)
    const int qck0 = q * 64 + ck0;            // K/V read base, slice 0
    const int qck1 = q * 64 + ck1;            // slice 1
    ushort* Pw = &Pb[wid][0];
    const int pw0 = q * 64 + (((g >> 1) + 0) ^ qs7) * 8 + (g & 1) * 4;  // j=0
    const int pw1 = q * 64 + (((g >> 1) + 2) ^ qs7) * 8 + (g & 1) * 4;  // j=1
    const int pw2 = q * 64 + (((g >> 1) + 4) ^ qs7) * 8 + (g & 1) * 4;  // j=2
    const int pw3 = q * 64 + (((g >> 1) + 6) ^ qs7) * 8 + (g & 1) * 4;  // j=3

    auto stage = [&](int buf, int kv0) {
        if (wid < 4) {
            const ushort* gsrc =
                qkv_h + (tokbase + kv0 + wid * 16) * 3072 + 1024 + h * 64;
            ushort* dst = &Kb[buf][wid * 1024];
#pragma unroll
            for (int is = 0; is < 2; ++is)
                gload_lds16(gsrc + (size_t)(is * 8 + kv_r) * 3072 + kv_csrc * 8,
                            dst + is * 512);
        } else {
            const ushort* gsrc = vT_h + vbase + (size_t)((wid - 4) * 16) * SEQ + kv0;
            ushort* dst = &Vb[buf][(wid - 4) * 1024];
#pragma unroll
            for (int is = 0; is < 2; ++is)
                gload_lds16(gsrc + (size_t)(is * 8 + kv_r) * SEQ + kv_csrc * 8,
                            dst + is * 512);
        }
    };

    stage(0, 0);  // 2 loads/wave in flight

    float l_ = 0.f;   // per-lane partial (deferred cross-lane reduce)
    f32x4 o[4];
#pragma unroll
    for (int i = 0; i < 4; ++i) o[i] = f32x4{0.f, 0.f, 0.f, 0.f};

    // per-tile body; cur is a compile-time constant at each call site
    auto body = [&](int cur) {
        const ushort* Kc = &Kb[cur][0];
        const ushort* Vc = &Vb[cur][0];

        // ---- S^T (pre-scaled): lane owns q-row q
        f32x4 s[4];
#pragma unroll
        for (int j = 0; j < 4; ++j) s[j] = f32x4{0.f, 0.f, 0.f, 0.f};
        __builtin_amdgcn_s_setprio(1);
#pragma unroll
        for (int j = 0; j < 4; ++j) {
            short8 kh0 = *(const short8*)&Kc[j * 1024 + qck0];
            s[j] = mfma16(kh0, qh[0], s[j]);
            short8 kh1 = *(const short8*)&Kc[j * 1024 + qck1];
            s[j] = mfma16(kh1, qh[1], s[j]);
        }
        __builtin_amdgcn_s_setprio(0);

        // ---- softmax: P = exp2(s) direct; accumulate per-lane l partial
        float rs = 0.f;
#pragma unroll
        for (int j = 0; j < 4; ++j) {
            ushort4 hv;
            float p0 = __builtin_exp2f(s[j][0]);
            float p1 = __builtin_exp2f(s[j][1]);
            float p2 = __builtin_exp2f(s[j][2]);
            float p3 = __builtin_exp2f(s[j][3]);
            rs += (p0 + p1) + (p2 + p3);
            hv.x = f2bf(p0);
            hv.y = f2bf(p1);
            hv.z = f2bf(p2);
            hv.w = f2bf(p3);
            const int off = (j == 0) ? pw0 : (j == 1) ? pw1 : (j == 2) ? pw2 : pw3;
            *(ushort4*)&Pw[off] = hv;
        }
        l_ += rs;
        asm volatile("s_waitcnt lgkmcnt(0)" ::: "memory");  // P visible to self
        __builtin_amdgcn_sched_barrier(0);

        // ---- O += P V
        __builtin_amdgcn_s_setprio(1);
#pragma unroll
        for (int ks = 0; ks < 2; ++ks) {
            short8 pa = *(const short8*)&Pw[ks ? qck1 : qck0];
#pragma unroll
            for (int jp = 0; jp < 4; ++jp) {
                short8 vh = *(const short8*)&Vc[jp * 1024 + (ks ? qck1 : qck0)];
                o[jp] = mfma16(pa, vh, o[jp]);
            }
        }
        __builtin_amdgcn_s_setprio(0);

        asm volatile("s_waitcnt lgkmcnt(0)" ::: "memory");  // cur reads retired
        __builtin_amdgcn_s_barrier();        // all waves done with cur
        __builtin_amdgcn_sched_barrier(0);
    };

    for (int kt2 = 0; kt2 < SEQ / 128; ++kt2) {
        // ---- sub 0: tile 2*kt2 in buf 0 (prefetch 2*kt2+1 -> buf 1)
        stage(1, (kt2 * 2 + 1) * 64);
        asm volatile("s_waitcnt vmcnt(2)" ::: "memory");
        __builtin_amdgcn_s_barrier();
        __builtin_amdgcn_sched_barrier(0);
        body(0);
        // ---- sub 1: tile 2*kt2+1 in buf 1 (prefetch 2*kt2+2 -> buf 0)
        if (kt2 < SEQ / 128 - 1) {
            stage(0, (kt2 * 2 + 2) * 64);
            asm volatile("s_waitcnt vmcnt(2)" ::: "memory");
        } else {
            asm volatile("s_waitcnt vmcnt(0)" ::: "memory");
        }
        __builtin_amdgcn_s_barrier();
        __builtin_amdgcn_sched_barrier(0);
        body(1);
    }

    // ---- epilogue: reduce l across the 4 g-groups, normalize, write bf16
    l_ += __shfl_xor(l_, 16);
    l_ += __shfl_xor(l_, 32);
    float inv = 1.f / l_;
#pragma unroll
    for (int r = 0; r < 4; ++r) {
        float invr = __shfl(inv, (g << 2) + r);
        int tok = q0 + wid * 16 + g * 4 + r;
        size_t rowb = (tokbase + tok) * 3072;
#pragma unroll
        for (int jp = 0; jp < 4; ++jp) {
            int col = h * 64 + jp * 16 + q;
            attn_h[rowb + col] = f2bf(o[jp][r] * invr);
        }
    }
}

// ---------------------------------------------------------------------------

extern "C" void kernel_launch(void* const* d_in, const int* in_sizes, int n_in,
                              void* d_out, int out_size, void* d_ws, size_t ws_size,
                              hipStream_t stream) {
    const float* x      = (const float*)d_in[0];  // [B,S,D]
    const float* W_attn = (const float*)d_in[1];  // [D,3D]
    const float* W_proj = (const float*)d_in[2];  // [D,D]

    const int M = BATCH * SEQ;  // 8192

    // ws layout (~72 MiB)
    ushort* qkv_h = (ushort*)d_ws;                    // [8192][3072]  48 MB
    ushort* WaT   = qkv_h + (size_t)M * 3072;         // [3072][1024]   6 MB
    ushort* WpT   = WaT + (size_t)3072 * 1024;        // [1024][1024]   2 MB
    ushort* vT_h  = WpT + (size_t)1024 * 1024;        // [4096][2048]  16 MB

    // d_out doubles as scratch for xh, then holds the final fp32 output
    ushort* xh = (ushort*)d_out;                      // [8192][1024]

    // 1) fused prep: x->bf16, W_attn^T (Q-cols CSC-scaled), W_proj^T
    prep_k<<<dim3(6144), 256, 0, stream>>>(x, W_attn, W_proj, xh, WaT, WpT);
    // 2) qkv = xh @ Wh_attn; V-column blocks also scatter vT (fused transpose)
    gemm_k<1, 1><<<dim3(24, 64), 256, 0, stream>>>(xh, 1024, 0, WaT,
                                                   qkv_h, nullptr, vT_h,
                                                   3072, 0, 1024);
    // 3) flash attention (8-wave, QBLK=128, XCD-aware flat grid, 48KB LDS)
    flash_mfma<<<dim3(1024), 512, 0, stream>>>(qkv_h, vT_h, qkv_h + 2048);
    // 4) out = attn @ W_proj (fp32 out, pure bf16 1-term, pipelined)
    gemm_k<0, 0><<<dim3(8, 64), 256, 0, stream>>>(qkv_h, 3072, 2048, WpT,
                                                  nullptr, (float*)d_out, nullptr,
                                                  1024, 0, 1024);
}

// Round 13
// 217.294 us; speedup vs baseline: 1.0825x; 1.0825x over previous
//
#include <hip/hip_runtime.h>
#include <hip/hip_bf16.h>

#define D_MODEL 1024
#define N_HEADS 16
#define SEQ     2048
#define BATCH   4
#define CSC     (0.125f * 1.44269504f)   // (1/sqrt(dk)) * log2(e)

typedef __attribute__((ext_vector_type(8))) short short8;
typedef __attribute__((ext_vector_type(4))) float f32x4;

__device__ __forceinline__ ushort f2bf(float v) {
    __hip_bfloat16 b = __float2bfloat16(v);
    return __builtin_bit_cast(ushort, b);
}
__device__ __forceinline__ f32x4 mfma16(short8 a, short8 b, f32x4 c) {
    return __builtin_amdgcn_mfma_f32_16x16x32_bf16(a, b, c, 0, 0, 0);
}
// async global->LDS, 16B/lane. LDS base must be wave-uniform; global addr per-lane.
__device__ __forceinline__ void gload_lds16(const ushort* g, ushort* l) {
    __builtin_amdgcn_global_load_lds(
        (const __attribute__((address_space(1))) unsigned int*)g,
        (__attribute__((address_space(3))) unsigned int*)l, 16, 0, 0);
}

// ---------------------------------------------------------------------------
// fused prep: block-range dispatch.
//   blocks [0,2048):        x fp32 -> bf16 hi (grid-stride float4)
//   blocks [2048,5120):     W_attn transpose -> WaT [3072][1024] bf16
//                           (Q-cols n<1024 pre-scaled by CSC in fp32 — exact)
//   blocks [5120,6144):     W_proj transpose -> WpT [1024][1024] bf16
// ---------------------------------------------------------------------------
__global__ __launch_bounds__(256) void prep_k(const float* __restrict__ x,
                                              const float* __restrict__ Wa,
                                              const float* __restrict__ Wp,
                                              ushort* __restrict__ xh,
                                              ushort* __restrict__ WaT,
                                              ushort* __restrict__ WpT) {
    const int id = blockIdx.x;
    const int t = threadIdx.x;
    if (id < 2048) {
        const float4* x4 = (const float4*)x;
        ushort4* xh4 = (ushort4*)xh;
        const int n4 = BATCH * SEQ * D_MODEL / 4;
        for (int i = id * 256 + t; i < n4; i += 2048 * 256) {
            float4 v = x4[i];
            ushort4 hv;
            hv.x = f2bf(v.x);
            hv.y = f2bf(v.y);
            hv.z = f2bf(v.z);
            hv.w = f2bf(v.w);
            xh4[i] = hv;
        }
    } else {
        __shared__ float tile[32][33];
        const float* W;
        ushort* WT;
        int N, tid, scaleQ;
        if (id < 2048 + 3072) { tid = id - 2048; W = Wa; WT = WaT; N = 3072; scaleQ = 1; }
        else                  { tid = id - 5120; W = Wp; WT = WpT; N = 1024; scaleQ = 0; }
        const int nb = (tid % (N / 32)) * 32, kb = (tid / (N / 32)) * 32;
        const int tx = t & 31, ty = t >> 5;
#pragma unroll
        for (int i = 0; i < 4; ++i)
            tile[ty + 8 * i][tx] = W[(size_t)(kb + ty + 8 * i) * N + nb + tx];
        __syncthreads();
#pragma unroll
        for (int i = 0; i < 4; ++i) {
            int n = nb + ty + 8 * i;
            float v = tile[tx][ty + 8 * i];  // = W[kb+tx][n]
            if (scaleQ && n < 1024) v *= CSC;
            WT[(size_t)n * 1024 + kb + tx] = f2bf(v);
        }
    }
}

// ---------------------------------------------------------------------------
// transpose v-columns of qkv (bf16 hi) into vT[(b*16+h)*64 + d][s]
// ---------------------------------------------------------------------------
__global__ __launch_bounds__(256) void transpose_v_k(const ushort* __restrict__ qkv_h,
                                                     ushort* __restrict__ vT_h) {
    __shared__ ushort th[64][68];
    const int st = blockIdx.x, h = blockIdx.y, b = blockIdx.z;
    const int t = threadIdx.x;
    const int s0 = st * 64;
    {
        int s = t >> 2, dc = (t & 3) * 16;
        const size_t src = ((size_t)(b * SEQ + s0 + s)) * 3072 + 2048 + h * 64 + dc;
        *(uint4*)&th[s][dc]     = *(const uint4*)&qkv_h[src];
        *(uint4*)&th[s][dc + 8] = *(const uint4*)&qkv_h[src + 8];
    }
    __syncthreads();
    {
        int d = t >> 2, sc = (t & 3) * 16;
        ushort bufh[16];
#pragma unroll
        for (int j = 0; j < 16; ++j) bufh[j] = th[sc + j][d];
        const size_t dst = ((size_t)((b * 16 + h) * 64 + d)) * SEQ + s0 + sc;
        *(uint4*)&vT_h[dst]     = *(uint4*)&bufh[0];
        *(uint4*)&vT_h[dst + 8] = *(uint4*)&bufh[8];
    }
}

// ---------------------------------------------------------------------------
// bf16 MFMA GEMM, pipelined, 1-term (Ah*Bh): C[M,N] = A @ B
// A row-major [.,K] (lda, col offset aoff); B as B^T row-major [N][K].
// 128x128 tile, BK=32, 4 waves (2x2), 4x4 16x16 frags/wave.
// Cooperative staging, double-buffered LDS, counted vmcnt + raw s_barrier.
// T1: XCD-aware bijective block remap (nwg % 8 == 0) — each XCD owns a
// contiguous run of tiles -> B-panel reuse in its private L2.
// ---------------------------------------------------------------------------
template <int OUT_SPLIT>
__global__ __launch_bounds__(256) void gemm_k(
    const ushort* __restrict__ Ah, int lda, int aoff,
    const ushort* __restrict__ BhT,
    ushort* __restrict__ Ch, float* __restrict__ Cf,
    int ldc, int coff, int K) {
    __shared__ __align__(16) ushort lds[2][2][4096];   // [buf][0=A,1=B]
    const int t = threadIdx.x;
    const int lane = t & 63, wid = t >> 6;
    const int wm = (wid >> 1) * 64, wn = (wid & 1) * 64;

    // XCD-aware remap (bijective since nwg % 8 == 0)
    const int gx = gridDim.x;
    const int nwg = gx * gridDim.y;
    const int flat = blockIdx.y * gx + blockIdx.x;
    const int swzid = (flat & 7) * (nwg >> 3) + (flat >> 3);
    const int row0 = (swzid / gx) * 128, col0 = (swzid % gx) * 128;

    f32x4 acc[4][4];
#pragma unroll
    for (int i = 0; i < 4; ++i)
#pragma unroll
        for (int j = 0; j < 4; ++j) acc[i][j] = f32x4{0.f, 0.f, 0.f, 0.f};

    const int r_loc = lane >> 2;                       // 0..15
    const int c_src = (lane & 3) ^ ((lane >> 3) & 3);  // pre-swizzled source col
    const int swz = ((lane & 15) >> 1) & 3;
    const int ch = (((lane >> 4) ^ swz) * 8);
    const int rA = wm + (lane & 15);
    const int rB = wn + (lane & 15);

    // each wave stages 4 chunks (1KB each); chunk c -> tile c>>3, rows (c&7)*16+
    auto stage = [&](int buf, int kk) {
#pragma unroll
        for (int ic = 0; ic < 4; ++ic) {
            const int c = wid * 4 + ic;
            const int tile = c >> 3, chi = c & 7;
            const ushort* s = tile ? BhT : Ah;
            const int sr = tile ? col0 : row0;
            const int sl = tile ? K : lda;
            const int so = tile ? 0 : aoff;
            const ushort* gp =
                s + (size_t)(sr + chi * 16 + r_loc) * sl + so + kk + c_src * 8;
            gload_lds16(gp, &lds[buf][tile][chi * 512 + 0]);
        }
    };

    stage(0, 0);
    for (int k0 = 0; k0 < K; k0 += 32) {
        const int cur = (k0 >> 5) & 1;
        if (k0 + 32 < K) {
            stage(cur ^ 1, k0 + 32);   // prefetch next K-tile
            asm volatile("s_waitcnt vmcnt(4)" ::: "memory");
        } else {
            asm volatile("s_waitcnt vmcnt(0)" ::: "memory");
        }
        __builtin_amdgcn_s_barrier();      // cur buffer landed (all waves)
        __builtin_amdgcn_sched_barrier(0);

        short8 ah[4], bh[4];
#pragma unroll
        for (int f = 0; f < 4; ++f) {
            ah[f] = *(const short8*)&lds[cur][0][(rA + f * 16) * 32 + ch];
            bh[f] = *(const short8*)&lds[cur][1][(rB + f * 16) * 32 + ch];
        }
        __builtin_amdgcn_s_setprio(1);
#pragma unroll
        for (int i = 0; i < 4; ++i)
#pragma unroll
            for (int j = 0; j < 4; ++j) acc[i][j] = mfma16(ah[i], bh[j], acc[i][j]);
        __builtin_amdgcn_s_setprio(0);
        asm volatile("s_waitcnt lgkmcnt(0)" ::: "memory");  // reads of cur retired
        __builtin_amdgcn_s_barrier();
        __builtin_amdgcn_sched_barrier(0);
    }
    // epilogue; C/D layout: row=(lane>>4)*4+reg, col=lane&15
#pragma unroll
    for (int i = 0; i < 4; ++i)
#pragma unroll
        for (int j = 0; j < 4; ++j)
#pragma unroll
            for (int r = 0; r < 4; ++r) {
                int row = row0 + wm + i * 16 + (lane >> 4) * 4 + r;
                int col = col0 + wn + j * 16 + (lane & 15);
                float v = acc[i][j][r];
                if (OUT_SPLIT) {
                    Ch[(size_t)row * ldc + coff + col] = f2bf(v);
                } else {
                    Cf[(size_t)row * ldc + coff + col] = v;
                }
            }
}

// ---------------------------------------------------------------------------
// MFMA flash attention (proven 120.5 us), pipelined, all bf16, 8 waves /
// QBLK=128. Q pre-scaled by CSC -> softmax = exp2(s) direct; no max-tracking;
// deferred l-reduction; kt-loop unrolled x2 (static buffer index). XCD-aware
// flat grid. K AND V double-buffered, counted vmcnt(2).
// ---------------------------------------------------------------------------
__global__ __launch_bounds__(512) void flash_mfma(
    const ushort* __restrict__ qkv_h, const ushort* __restrict__ vT_h,
    ushort* __restrict__ attn_h) {
    const int id = blockIdx.x;
    const int bh = id & 63, qt = id >> 6;
    const int h = bh & 15, b = bh >> 4;
    const int t = threadIdx.x, lane = t & 63, wid = t >> 6;  // wid 0..7
    const int q = lane & 15, g = lane >> 4;
    const int qs7 = q & 7;

    __shared__ __align__(16) ushort Kb[2][4096];   // 8 KB per buf (64x64)
    __shared__ __align__(16) ushort Vb[2][4096];
    __shared__ __align__(16) ushort Pb[8][1024];   // 2 KB per wave

    const size_t tokbase = (size_t)b * SEQ;
    const int q0 = qt * 128;
    const int kv_r = lane >> 3;
    const int kv_csrc = (lane & 7) ^ ((lane >> 3) & 7);
    const size_t vbase = ((size_t)(b * 16 + h) * 64) * SEQ;

    // ---- stage Q (128 rows) into Kb[0..1] (16 KB contiguous): 16 chunks
    ushort* KQ = &Kb[0][0];
#pragma unroll
    for (int is = 0; is < 2; ++is) {
        int ci = wid * 2 + is;
        const ushort* gq =
            qkv_h + (tokbase + q0 + ci * 8 + kv_r) * 3072 + h * 64 + kv_csrc * 8;
        gload_lds16(gq, KQ + ci * 512);
    }
    __syncthreads();  // drains vmcnt -> Q landed
    const int ck0 = (g ^ qs7) * 8;
    const int ck1 = ((g + 4) ^ qs7) * 8;
    short8 qh[2];
    {
        const int row = wid * 16 + q;
        qh[0] = *(const short8*)&KQ[row * 64 + ck0];
        qh[1] = *(const short8*)&KQ[row * 64 + ck1];
    }
    __syncthreads();  // frag reads retired before K overwrites

    // hoisted per-lane LDS offsets (kt-invariant)
    const int qck0 = q * 64 + ck0;            // K/V read base, slice 0
    const int qck1 = q * 64 + ck1;            // slice 1
    ushort* Pw = &Pb[wid][0];
    const int pw0 = q * 64 + (((g >> 1) + 0) ^ qs7) * 8 + (g & 1) * 4;  // j=0
    const int pw1 = q * 64 + (((g >> 1) + 2) ^ qs7) * 8 + (g & 1) * 4;  // j=1
    const int pw2 = q * 64 + (((g >> 1) + 4) ^ qs7) * 8 + (g & 1) * 4;  // j=2
    const int pw3 = q * 64 + (((g >> 1) + 6) ^ qs7) * 8 + (g & 1) * 4;  // j=3

    auto stage = [&](int buf, int kv0) {
        if (wid < 4) {
            const ushort* gsrc =
                qkv_h + (tokbase + kv0 + wid * 16) * 3072 + 1024 + h * 64;
            ushort* dst = &Kb[buf][wid * 1024];
#pragma unroll
            for (int is = 0; is < 2; ++is)
                gload_lds16(gsrc + (size_t)(is * 8 + kv_r) * 3072 + kv_csrc * 8,
                            dst + is * 512);
        } else {
            const ushort* gsrc = vT_h + vbase + (size_t)((wid - 4) * 16) * SEQ + kv0;
            ushort* dst = &Vb[buf][(wid - 4) * 1024];
#pragma unroll
            for (int is = 0; is < 2; ++is)
                gload_lds16(gsrc + (size_t)(is * 8 + kv_r) * SEQ + kv_csrc * 8,
                            dst + is * 512);
        }
    };

    stage(0, 0);  // 2 loads/wave in flight

    float l_ = 0.f;   // per-lane partial (deferred cross-lane reduce)
    f32x4 o[4];
#pragma unroll
    for (int i = 0; i < 4; ++i) o[i] = f32x4{0.f, 0.f, 0.f, 0.f};

    // per-tile body; cur is a compile-time constant at each call site
    auto body = [&](int cur) {
        const ushort* Kc = &Kb[cur][0];
        const ushort* Vc = &Vb[cur][0];

        // ---- S^T (pre-scaled): lane owns q-row q
        f32x4 s[4];
#pragma unroll
        for (int j = 0; j < 4; ++j) s[j] = f32x4{0.f, 0.f, 0.f, 0.f};
        __builtin_amdgcn_s_setprio(1);
#pragma unroll
        for (int j = 0; j < 4; ++j) {
            short8 kh0 = *(const short8*)&Kc[j * 1024 + qck0];
            s[j] = mfma16(kh0, qh[0], s[j]);
            short8 kh1 = *(const short8*)&Kc[j * 1024 + qck1];
            s[j] = mfma16(kh1, qh[1], s[j]);
        }
        __builtin_amdgcn_s_setprio(0);

        // ---- softmax: P = exp2(s) direct; accumulate per-lane l partial
        float rs = 0.f;
#pragma unroll
        for (int j = 0; j < 4; ++j) {
            ushort4 hv;
            float p0 = __builtin_exp2f(s[j][0]);
            float p1 = __builtin_exp2f(s[j][1]);
            float p2 = __builtin_exp2f(s[j][2]);
            float p3 = __builtin_exp2f(s[j][3]);
            rs += (p0 + p1) + (p2 + p3);
            hv.x = f2bf(p0);
            hv.y = f2bf(p1);
            hv.z = f2bf(p2);
            hv.w = f2bf(p3);
            const int off = (j == 0) ? pw0 : (j == 1) ? pw1 : (j == 2) ? pw2 : pw3;
            *(ushort4*)&Pw[off] = hv;
        }
        l_ += rs;
        asm volatile("s_waitcnt lgkmcnt(0)" ::: "memory");  // P visible to self
        __builtin_amdgcn_sched_barrier(0);

        // ---- O += P V
        __builtin_amdgcn_s_setprio(1);
#pragma unroll
        for (int ks = 0; ks < 2; ++ks) {
            short8 pa = *(const short8*)&Pw[ks ? qck1 : qck0];
#pragma unroll
            for (int jp = 0; jp < 4; ++jp) {
                short8 vh = *(const short8*)&Vc[jp * 1024 + (ks ? qck1 : qck0)];
                o[jp] = mfma16(pa, vh, o[jp]);
            }
        }
        __builtin_amdgcn_s_setprio(0);

        asm volatile("s_waitcnt lgkmcnt(0)" ::: "memory");  // cur reads retired
        __builtin_amdgcn_s_barrier();        // all waves done with cur
        __builtin_amdgcn_sched_barrier(0);
    };

    for (int kt2 = 0; kt2 < SEQ / 128; ++kt2) {
        // ---- sub 0: tile 2*kt2 in buf 0 (prefetch 2*kt2+1 -> buf 1)
        stage(1, (kt2 * 2 + 1) * 64);
        asm volatile("s_waitcnt vmcnt(2)" ::: "memory");
        __builtin_amdgcn_s_barrier();
        __builtin_amdgcn_sched_barrier(0);
        body(0);
        // ---- sub 1: tile 2*kt2+1 in buf 1 (prefetch 2*kt2+2 -> buf 0)
        if (kt2 < SEQ / 128 - 1) {
            stage(0, (kt2 * 2 + 2) * 64);
            asm volatile("s_waitcnt vmcnt(2)" ::: "memory");
        } else {
            asm volatile("s_waitcnt vmcnt(0)" ::: "memory");
        }
        __builtin_amdgcn_s_barrier();
        __builtin_amdgcn_sched_barrier(0);
        body(1);
    }

    // ---- epilogue: reduce l across the 4 g-groups, normalize, write bf16
    l_ += __shfl_xor(l_, 16);
    l_ += __shfl_xor(l_, 32);
    float inv = 1.f / l_;
#pragma unroll
    for (int r = 0; r < 4; ++r) {
        float invr = __shfl(inv, (g << 2) + r);
        int tok = q0 + wid * 16 + g * 4 + r;
        size_t rowb = (tokbase + tok) * 3072;
#pragma unroll
        for (int jp = 0; jp < 4; ++jp) {
            int col = h * 64 + jp * 16 + q;
            attn_h[rowb + col] = f2bf(o[jp][r] * invr);
        }
    }
}

// ---------------------------------------------------------------------------

extern "C" void kernel_launch(void* const* d_in, const int* in_sizes, int n_in,
                              void* d_out, int out_size, void* d_ws, size_t ws_size,
                              hipStream_t stream) {
    const float* x      = (const float*)d_in[0];  // [B,S,D]
    const float* W_attn = (const float*)d_in[1];  // [D,3D]
    const float* W_proj = (const float*)d_in[2];  // [D,D]

    const int M = BATCH * SEQ;  // 8192

    // ws layout (~72 MiB)
    ushort* qkv_h = (ushort*)d_ws;                    // [8192][3072]  48 MB
    ushort* WaT   = qkv_h + (size_t)M * 3072;         // [3072][1024]   6 MB
    ushort* WpT   = WaT + (size_t)3072 * 1024;        // [1024][1024]   2 MB
    ushort* vT_h  = WpT + (size_t)1024 * 1024;        // [4096][2048]  16 MB

    // d_out doubles as scratch for xh, then holds the final fp32 output
    ushort* xh = (ushort*)d_out;                      // [8192][1024]

    // 1) fused prep: x->bf16, W_attn^T (Q-cols CSC-scaled), W_proj^T
    prep_k<<<dim3(6144), 256, 0, stream>>>(x, W_attn, W_proj, xh, WaT, WpT);
    // 2) qkv = xh @ Wh_attn (pure bf16, pipelined, XCD-swizzled grid)
    gemm_k<1><<<dim3(24, 64), 256, 0, stream>>>(xh, 1024, 0, WaT,
                                                qkv_h, nullptr, 3072, 0, 1024);
    // 3) v columns -> vT (d_ws)
    transpose_v_k<<<dim3(32, 16, 4), 256, 0, stream>>>(qkv_h, vT_h);
    // 4) flash attention (8-wave, QBLK=128, XCD-aware flat grid, 48KB LDS)
    flash_mfma<<<dim3(1024), 512, 0, stream>>>(qkv_h, vT_h, qkv_h + 2048);
    // 5) out = attn @ W_proj (fp32 out, pure bf16, pipelined, XCD-swizzled)
    gemm_k<0><<<dim3(8, 64), 256, 0, stream>>>(qkv_h, 3072, 2048, WpT,
                                               nullptr, (float*)d_out, 1024, 0,
                                               1024);
}

// Round 14
// 212.854 us; speedup vs baseline: 1.1051x; 1.0209x over previous
//
#include <hip/hip_runtime.h>
#include <hip/hip_bf16.h>

#define D_MODEL 1024
#define N_HEADS 16
#define SEQ     2048
#define BATCH   4
#define CSC     (0.125f * 1.44269504f)   // (1/sqrt(dk)) * log2(e)

typedef __attribute__((ext_vector_type(8))) short short8;
typedef __attribute__((ext_vector_type(4))) float f32x4;

__device__ __forceinline__ ushort f2bf(float v) {
    __hip_bfloat16 b = __float2bfloat16(v);
    return __builtin_bit_cast(ushort, b);
}
__device__ __forceinline__ f32x4 mfma16(short8 a, short8 b, f32x4 c) {
    return __builtin_amdgcn_mfma_f32_16x16x32_bf16(a, b, c, 0, 0, 0);
}
// async global->LDS, 16B/lane. LDS base must be wave-uniform; global addr per-lane.
__device__ __forceinline__ void gload_lds16(const ushort* g, ushort* l) {
    __builtin_amdgcn_global_load_lds(
        (const __attribute__((address_space(1))) unsigned int*)g,
        (__attribute__((address_space(3))) unsigned int*)l, 16, 0, 0);
}

// ---------------------------------------------------------------------------
// fused prep: block-range dispatch.
//   blocks [0,2048):        x fp32 -> bf16 hi (grid-stride float4)
//   blocks [2048,5120):     W_attn transpose -> WaT [3072][1024] bf16
//                           (Q-cols n<1024 pre-scaled by CSC in fp32 — exact)
//   blocks [5120,6144):     W_proj transpose -> WpT [1024][1024] bf16
// ---------------------------------------------------------------------------
__global__ __launch_bounds__(256) void prep_k(const float* __restrict__ x,
                                              const float* __restrict__ Wa,
                                              const float* __restrict__ Wp,
                                              ushort* __restrict__ xh,
                                              ushort* __restrict__ WaT,
                                              ushort* __restrict__ WpT) {
    const int id = blockIdx.x;
    const int t = threadIdx.x;
    if (id < 2048) {
        const float4* x4 = (const float4*)x;
        ushort4* xh4 = (ushort4*)xh;
        const int n4 = BATCH * SEQ * D_MODEL / 4;
        for (int i = id * 256 + t; i < n4; i += 2048 * 256) {
            float4 v = x4[i];
            ushort4 hv;
            hv.x = f2bf(v.x);
            hv.y = f2bf(v.y);
            hv.z = f2bf(v.z);
            hv.w = f2bf(v.w);
            xh4[i] = hv;
        }
    } else {
        __shared__ float tile[32][33];
        const float* W;
        ushort* WT;
        int N, tid, scaleQ;
        if (id < 2048 + 3072) { tid = id - 2048; W = Wa; WT = WaT; N = 3072; scaleQ = 1; }
        else                  { tid = id - 5120; W = Wp; WT = WpT; N = 1024; scaleQ = 0; }
        const int nb = (tid % (N / 32)) * 32, kb = (tid / (N / 32)) * 32;
        const int tx = t & 31, ty = t >> 5;
#pragma unroll
        for (int i = 0; i < 4; ++i)
            tile[ty + 8 * i][tx] = W[(size_t)(kb + ty + 8 * i) * N + nb + tx];
        __syncthreads();
#pragma unroll
        for (int i = 0; i < 4; ++i) {
            int n = nb + ty + 8 * i;
            float v = tile[tx][ty + 8 * i];  // = W[kb+tx][n]
            if (scaleQ && n < 1024) v *= CSC;
            WT[(size_t)n * 1024 + kb + tx] = f2bf(v);
        }
    }
}

// ---------------------------------------------------------------------------
// transpose v-columns of qkv (bf16 hi) into vT[(b*16+h)*64 + d][s'], where
// s' permutes keys within each 64-block by pi(k) = 8*((k>>2)&3) +
// 32*((k>>5)&1) + 4*((k>>4)&1) + (k&3). This makes each flash lane's QK^T
// output registers directly usable as the PV A-fragment (no P LDS roundtrip).
// ---------------------------------------------------------------------------
__global__ __launch_bounds__(256) void transpose_v_k(const ushort* __restrict__ qkv_h,
                                                     ushort* __restrict__ vT_h) {
    __shared__ ushort th[64][68];
    const int st = blockIdx.x, h = blockIdx.y, b = blockIdx.z;
    const int t = threadIdx.x;
    const int s0 = st * 64;
    {
        int s = t >> 2, dc = (t & 3) * 16;
        const size_t src = ((size_t)(b * SEQ + s0 + s)) * 3072 + 2048 + h * 64 + dc;
        *(uint4*)&th[s][dc]     = *(const uint4*)&qkv_h[src];
        *(uint4*)&th[s][dc + 8] = *(const uint4*)&qkv_h[src + 8];
    }
    __syncthreads();
    {
        int d = t >> 2, sc = (t & 3) * 16;
        // pi on k = sc + 4*jj + r: (k>>2)&3 = jj, so k' = 8*jj + c_off + r
        const int c_off = ((sc & 16) ? 4 : 0) + ((sc & 32) ? 32 : 0);
        const size_t dstbase = ((size_t)((b * 16 + h) * 64 + d)) * SEQ + s0;
#pragma unroll
        for (int jj = 0; jj < 4; ++jj) {
            ushort4 v;
            v.x = th[sc + 4 * jj + 0][d];
            v.y = th[sc + 4 * jj + 1][d];
            v.z = th[sc + 4 * jj + 2][d];
            v.w = th[sc + 4 * jj + 3][d];
            *(ushort4*)&vT_h[dstbase + 8 * jj + c_off] = v;
        }
    }
}

// ---------------------------------------------------------------------------
// bf16 MFMA GEMM, pipelined, 1-term (Ah*Bh): C[M,N] = A @ B
// A row-major [.,K] (lda, col offset aoff); B as B^T row-major [N][K].
// 128x128 tile, BK=32, 4 waves (2x2), 4x4 16x16 frags/wave.
// Cooperative staging, double-buffered LDS, counted vmcnt + raw s_barrier.
// T1: XCD-aware bijective block remap (nwg % 8 == 0).
// ---------------------------------------------------------------------------
template <int OUT_SPLIT>
__global__ __launch_bounds__(256) void gemm_k(
    const ushort* __restrict__ Ah, int lda, int aoff,
    const ushort* __restrict__ BhT,
    ushort* __restrict__ Ch, float* __restrict__ Cf,
    int ldc, int coff, int K) {
    __shared__ __align__(16) ushort lds[2][2][4096];   // [buf][0=A,1=B]
    const int t = threadIdx.x;
    const int lane = t & 63, wid = t >> 6;
    const int wm = (wid >> 1) * 64, wn = (wid & 1) * 64;

    // XCD-aware remap (bijective since nwg % 8 == 0)
    const int gx = gridDim.x;
    const int nwg = gx * gridDim.y;
    const int flat = blockIdx.y * gx + blockIdx.x;
    const int swzid = (flat & 7) * (nwg >> 3) + (flat >> 3);
    const int row0 = (swzid / gx) * 128, col0 = (swzid % gx) * 128;

    f32x4 acc[4][4];
#pragma unroll
    for (int i = 0; i < 4; ++i)
#pragma unroll
        for (int j = 0; j < 4; ++j) acc[i][j] = f32x4{0.f, 0.f, 0.f, 0.f};

    const int r_loc = lane >> 2;                       // 0..15
    const int c_src = (lane & 3) ^ ((lane >> 3) & 3);  // pre-swizzled source col
    const int swz = ((lane & 15) >> 1) & 3;
    const int ch = (((lane >> 4) ^ swz) * 8);
    const int rA = wm + (lane & 15);
    const int rB = wn + (lane & 15);

    // each wave stages 4 chunks (1KB each); chunk c -> tile c>>3, rows (c&7)*16+
    auto stage = [&](int buf, int kk) {
#pragma unroll
        for (int ic = 0; ic < 4; ++ic) {
            const int c = wid * 4 + ic;
            const int tile = c >> 3, chi = c & 7;
            const ushort* s = tile ? BhT : Ah;
            const int sr = tile ? col0 : row0;
            const int sl = tile ? K : lda;
            const int so = tile ? 0 : aoff;
            const ushort* gp =
                s + (size_t)(sr + chi * 16 + r_loc) * sl + so + kk + c_src * 8;
            gload_lds16(gp, &lds[buf][tile][chi * 512 + 0]);
        }
    };

    stage(0, 0);
    for (int k0 = 0; k0 < K; k0 += 32) {
        const int cur = (k0 >> 5) & 1;
        if (k0 + 32 < K) {
            stage(cur ^ 1, k0 + 32);   // prefetch next K-tile
            asm volatile("s_waitcnt vmcnt(4)" ::: "memory");
        } else {
            asm volatile("s_waitcnt vmcnt(0)" ::: "memory");
        }
        __builtin_amdgcn_s_barrier();      // cur buffer landed (all waves)
        __builtin_amdgcn_sched_barrier(0);

        short8 ah[4], bh[4];
#pragma unroll
        for (int f = 0; f < 4; ++f) {
            ah[f] = *(const short8*)&lds[cur][0][(rA + f * 16) * 32 + ch];
            bh[f] = *(const short8*)&lds[cur][1][(rB + f * 16) * 32 + ch];
        }
        __builtin_amdgcn_s_setprio(1);
#pragma unroll
        for (int i = 0; i < 4; ++i)
#pragma unroll
            for (int j = 0; j < 4; ++j) acc[i][j] = mfma16(ah[i], bh[j], acc[i][j]);
        __builtin_amdgcn_s_setprio(0);
        asm volatile("s_waitcnt lgkmcnt(0)" ::: "memory");  // reads of cur retired
        __builtin_amdgcn_s_barrier();
        __builtin_amdgcn_sched_barrier(0);
    }
    // epilogue; C/D layout: row=(lane>>4)*4+reg, col=lane&15
#pragma unroll
    for (int i = 0; i < 4; ++i)
#pragma unroll
        for (int j = 0; j < 4; ++j)
#pragma unroll
            for (int r = 0; r < 4; ++r) {
                int row = row0 + wm + i * 16 + (lane >> 4) * 4 + r;
                int col = col0 + wn + j * 16 + (lane & 15);
                float v = acc[i][j][r];
                if (OUT_SPLIT) {
                    Ch[(size_t)row * ldc + coff + col] = f2bf(v);
                } else {
                    Cf[(size_t)row * ldc + coff + col] = v;
                }
            }
}

// ---------------------------------------------------------------------------
// MFMA flash attention, pipelined, all bf16, 8 waves / QBLK=128.
// Q pre-scaled by CSC -> softmax = exp2(s) direct; no max-tracking; deferred
// l-reduction; kt-loop unrolled x2 (static buffer index). XCD-aware flat
// grid. K AND V double-buffered, counted vmcnt(2).
// P never touches LDS: V keys are pi-permuted (see transpose_v_k), so the
// QK^T output registers p[j][r] pack directly into the PV A-fragment
// (pa[0]=[p0|p1], pa[1]=[p2|p3]). LDS = 32 KB -> all 1024 blocks resident
// (4/CU needed, 5/CU possible) -> no tail round.
// ---------------------------------------------------------------------------
__global__ __launch_bounds__(512) void flash_mfma(
    const ushort* __restrict__ qkv_h, const ushort* __restrict__ vT_h,
    ushort* __restrict__ attn_h) {
    const int id = blockIdx.x;
    const int bh = id & 63, qt = id >> 6;
    const int h = bh & 15, b = bh >> 4;
    const int t = threadIdx.x, lane = t & 63, wid = t >> 6;  // wid 0..7
    const int q = lane & 15, g = lane >> 4;
    const int qs7 = q & 7;

    __shared__ __align__(16) ushort Kb[2][4096];   // 8 KB per buf (64x64)
    __shared__ __align__(16) ushort Vb[2][4096];

    const size_t tokbase = (size_t)b * SEQ;
    const int q0 = qt * 128;
    const int kv_r = lane >> 3;
    const int kv_csrc = (lane & 7) ^ ((lane >> 3) & 7);
    const size_t vbase = ((size_t)(b * 16 + h) * 64) * SEQ;

    // ---- stage Q (128 rows) into Kb[0..1] (16 KB contiguous): 16 chunks
    ushort* KQ = &Kb[0][0];
#pragma unroll
    for (int is = 0; is < 2; ++is) {
        int ci = wid * 2 + is;
        const ushort* gq =
            qkv_h + (tokbase + q0 + ci * 8 + kv_r) * 3072 + h * 64 + kv_csrc * 8;
        gload_lds16(gq, KQ + ci * 512);
    }
    __syncthreads();  // drains vmcnt -> Q landed
    const int ck0 = (g ^ qs7) * 8;
    const int ck1 = ((g + 4) ^ qs7) * 8;
    short8 qh[2];
    {
        const int row = wid * 16 + q;
        qh[0] = *(const short8*)&KQ[row * 64 + ck0];
        qh[1] = *(const short8*)&KQ[row * 64 + ck1];
    }
    __syncthreads();  // frag reads retired before K overwrites

    // hoisted per-lane LDS offsets (kt-invariant)
    const int qck0 = q * 64 + ck0;            // K/V read base, slice 0
    const int qck1 = q * 64 + ck1;            // slice 1

    auto stage = [&](int buf, int kv0) {
        if (wid < 4) {
            const ushort* gsrc =
                qkv_h + (tokbase + kv0 + wid * 16) * 3072 + 1024 + h * 64;
            ushort* dst = &Kb[buf][wid * 1024];
#pragma unroll
            for (int is = 0; is < 2; ++is)
                gload_lds16(gsrc + (size_t)(is * 8 + kv_r) * 3072 + kv_csrc * 8,
                            dst + is * 512);
        } else {
            const ushort* gsrc = vT_h + vbase + (size_t)((wid - 4) * 16) * SEQ + kv0;
            ushort* dst = &Vb[buf][(wid - 4) * 1024];
#pragma unroll
            for (int is = 0; is < 2; ++is)
                gload_lds16(gsrc + (size_t)(is * 8 + kv_r) * SEQ + kv_csrc * 8,
                            dst + is * 512);
        }
    };

    stage(0, 0);  // 2 loads/wave in flight

    float l_ = 0.f;   // per-lane partial (deferred cross-lane reduce)
    f32x4 o[4];
#pragma unroll
    for (int i = 0; i < 4; ++i) o[i] = f32x4{0.f, 0.f, 0.f, 0.f};

    // per-tile body; cur is a compile-time constant at each call site
    auto body = [&](int cur) {
        const ushort* Kc = &Kb[cur][0];
        const ushort* Vc = &Vb[cur][0];

        // ---- S^T (pre-scaled): lane owns q-row q; s[j][r] = key 16j+4g+r
        f32x4 s[4];
#pragma unroll
        for (int j = 0; j < 4; ++j) s[j] = f32x4{0.f, 0.f, 0.f, 0.f};
        __builtin_amdgcn_s_setprio(1);
#pragma unroll
        for (int j = 0; j < 4; ++j) {
            short8 kh0 = *(const short8*)&Kc[j * 1024 + qck0];
            s[j] = mfma16(kh0, qh[0], s[j]);
            short8 kh1 = *(const short8*)&Kc[j * 1024 + qck1];
            s[j] = mfma16(kh1, qh[1], s[j]);
        }
        __builtin_amdgcn_s_setprio(0);

        // ---- softmax: P = exp2(s); pack straight into PV A-fragments.
        // pi-permuted V makes register order == fragment order:
        // pa[j>>1] elements (j&1)*4+r  <->  key 16j+4g+r.
        float rs = 0.f;
        short8 pa[2];
#pragma unroll
        for (int j = 0; j < 4; ++j) {
            float p0 = __builtin_exp2f(s[j][0]);
            float p1 = __builtin_exp2f(s[j][1]);
            float p2 = __builtin_exp2f(s[j][2]);
            float p3 = __builtin_exp2f(s[j][3]);
            rs += (p0 + p1) + (p2 + p3);
            pa[j >> 1][(j & 1) * 4 + 0] = (short)f2bf(p0);
            pa[j >> 1][(j & 1) * 4 + 1] = (short)f2bf(p1);
            pa[j >> 1][(j & 1) * 4 + 2] = (short)f2bf(p2);
            pa[j >> 1][(j & 1) * 4 + 3] = (short)f2bf(p3);
        }
        l_ += rs;

        // ---- O += P V (P in registers, V pi-permuted in LDS)
        __builtin_amdgcn_s_setprio(1);
#pragma unroll
        for (int ks = 0; ks < 2; ++ks) {
#pragma unroll
            for (int jp = 0; jp < 4; ++jp) {
                short8 vh = *(const short8*)&Vc[jp * 1024 + (ks ? qck1 : qck0)];
                o[jp] = mfma16(pa[ks], vh, o[jp]);
            }
        }
        __builtin_amdgcn_s_setprio(0);

        asm volatile("s_waitcnt lgkmcnt(0)" ::: "memory");  // cur reads retired
        __builtin_amdgcn_s_barrier();        // all waves done with cur
        __builtin_amdgcn_sched_barrier(0);
    };

    for (int kt2 = 0; kt2 < SEQ / 128; ++kt2) {
        // ---- sub 0: tile 2*kt2 in buf 0 (prefetch 2*kt2+1 -> buf 1)
        stage(1, (kt2 * 2 + 1) * 64);
        asm volatile("s_waitcnt vmcnt(2)" ::: "memory");
        __builtin_amdgcn_s_barrier();
        __builtin_amdgcn_sched_barrier(0);
        body(0);
        // ---- sub 1: tile 2*kt2+1 in buf 1 (prefetch 2*kt2+2 -> buf 0)
        if (kt2 < SEQ / 128 - 1) {
            stage(0, (kt2 * 2 + 2) * 64);
            asm volatile("s_waitcnt vmcnt(2)" ::: "memory");
        } else {
            asm volatile("s_waitcnt vmcnt(0)" ::: "memory");
        }
        __builtin_amdgcn_s_barrier();
        __builtin_amdgcn_sched_barrier(0);
        body(1);
    }

    // ---- epilogue: reduce l across the 4 g-groups, normalize, write bf16
    l_ += __shfl_xor(l_, 16);
    l_ += __shfl_xor(l_, 32);
    float inv = 1.f / l_;
#pragma unroll
    for (int r = 0; r < 4; ++r) {
        float invr = __shfl(inv, (g << 2) + r);
        int tok = q0 + wid * 16 + g * 4 + r;
        size_t rowb = (tokbase + tok) * 3072;
#pragma unroll
        for (int jp = 0; jp < 4; ++jp) {
            int col = h * 64 + jp * 16 + q;
            attn_h[rowb + col] = f2bf(o[jp][r] * invr);
        }
    }
}

// ---------------------------------------------------------------------------

extern "C" void kernel_launch(void* const* d_in, const int* in_sizes, int n_in,
                              void* d_out, int out_size, void* d_ws, size_t ws_size,
                              hipStream_t stream) {
    const float* x      = (const float*)d_in[0];  // [B,S,D]
    const float* W_attn = (const float*)d_in[1];  // [D,3D]
    const float* W_proj = (const float*)d_in[2];  // [D,D]

    const int M = BATCH * SEQ;  // 8192

    // ws layout (~72 MiB)
    ushort* qkv_h = (ushort*)d_ws;                    // [8192][3072]  48 MB
    ushort* WaT   = qkv_h + (size_t)M * 3072;         // [3072][1024]   6 MB
    ushort* WpT   = WaT + (size_t)3072 * 1024;        // [1024][1024]   2 MB
    ushort* vT_h  = WpT + (size_t)1024 * 1024;        // [4096][2048]  16 MB

    // d_out doubles as scratch for xh, then holds the final fp32 output
    ushort* xh = (ushort*)d_out;                      // [8192][1024]

    // 1) fused prep: x->bf16, W_attn^T (Q-cols CSC-scaled), W_proj^T
    prep_k<<<dim3(6144), 256, 0, stream>>>(x, W_attn, W_proj, xh, WaT, WpT);
    // 2) qkv = xh @ Wh_attn (pure bf16, pipelined, XCD-swizzled grid)
    gemm_k<1><<<dim3(24, 64), 256, 0, stream>>>(xh, 1024, 0, WaT,
                                                qkv_h, nullptr, 3072, 0, 1024);
    // 3) v columns -> vT (pi-permuted keys, d_ws)
    transpose_v_k<<<dim3(32, 16, 4), 256, 0, stream>>>(qkv_h, vT_h);
    // 4) flash attention (8-wave, QBLK=128, XCD-aware flat grid, 32KB LDS)
    flash_mfma<<<dim3(1024), 512, 0, stream>>>(qkv_h, vT_h, qkv_h + 2048);
    // 5) out = attn @ W_proj (fp32 out, pure bf16, pipelined, XCD-swizzled)
    gemm_k<0><<<dim3(8, 64), 256, 0, stream>>>(qkv_h, 3072, 2048, WpT,
                                               nullptr, (float*)d_out, 1024, 0,
                                               1024);
}

// Round 15
// 209.824 us; speedup vs baseline: 1.1210x; 1.0144x over previous
//
#include <hip/hip_runtime.h>
#include <hip/hip_bf16.h>

#define D_MODEL 1024
#define N_HEADS 16
#define SEQ     2048
#define BATCH   4
#define CSC     (0.125f * 1.44269504f)   // (1/sqrt(dk)) * log2(e)

typedef __attribute__((ext_vector_type(8))) short short8;
typedef __attribute__((ext_vector_type(4))) float f32x4;

__device__ __forceinline__ ushort f2bf(float v) {
    __hip_bfloat16 b = __float2bfloat16(v);
    return __builtin_bit_cast(ushort, b);
}
__device__ __forceinline__ f32x4 mfma16(short8 a, short8 b, f32x4 c) {
    return __builtin_amdgcn_mfma_f32_16x16x32_bf16(a, b, c, 0, 0, 0);
}
// async global->LDS, 16B/lane. LDS base must be wave-uniform; global addr per-lane.
__device__ __forceinline__ void gload_lds16(const ushort* g, ushort* l) {
    __builtin_amdgcn_global_load_lds(
        (const __attribute__((address_space(1))) unsigned int*)g,
        (__attribute__((address_space(3))) unsigned int*)l, 16, 0, 0);
}

// ---------------------------------------------------------------------------
// fused prep: block-range dispatch.
//   blocks [0,2048):        x fp32 -> bf16 hi (grid-stride float4)
//   blocks [2048,5120):     W_attn transpose -> WaT [3072][1024] bf16
//                           (Q-cols n<1024 pre-scaled by CSC in fp32 — exact)
//   blocks [5120,6144):     W_proj transpose -> WpT [1024][1024] bf16
// ---------------------------------------------------------------------------
__global__ __launch_bounds__(256) void prep_k(const float* __restrict__ x,
                                              const float* __restrict__ Wa,
                                              const float* __restrict__ Wp,
                                              ushort* __restrict__ xh,
                                              ushort* __restrict__ WaT,
                                              ushort* __restrict__ WpT) {
    const int id = blockIdx.x;
    const int t = threadIdx.x;
    if (id < 2048) {
        const float4* x4 = (const float4*)x;
        ushort4* xh4 = (ushort4*)xh;
        const int n4 = BATCH * SEQ * D_MODEL / 4;
        for (int i = id * 256 + t; i < n4; i += 2048 * 256) {
            float4 v = x4[i];
            ushort4 hv;
            hv.x = f2bf(v.x);
            hv.y = f2bf(v.y);
            hv.z = f2bf(v.z);
            hv.w = f2bf(v.w);
            xh4[i] = hv;
        }
    } else {
        __shared__ float tile[32][33];
        const float* W;
        ushort* WT;
        int N, tid, scaleQ;
        if (id < 2048 + 3072) { tid = id - 2048; W = Wa; WT = WaT; N = 3072; scaleQ = 1; }
        else                  { tid = id - 5120; W = Wp; WT = WpT; N = 1024; scaleQ = 0; }
        const int nb = (tid % (N / 32)) * 32, kb = (tid / (N / 32)) * 32;
        const int tx = t & 31, ty = t >> 5;
#pragma unroll
        for (int i = 0; i < 4; ++i)
            tile[ty + 8 * i][tx] = W[(size_t)(kb + ty + 8 * i) * N + nb + tx];
        __syncthreads();
#pragma unroll
        for (int i = 0; i < 4; ++i) {
            int n = nb + ty + 8 * i;
            float v = tile[tx][ty + 8 * i];  // = W[kb+tx][n]
            if (scaleQ && n < 1024) v *= CSC;
            WT[(size_t)n * 1024 + kb + tx] = f2bf(v);
        }
    }
}

// ---------------------------------------------------------------------------
// transpose v-columns of qkv (bf16 hi) into vT[(b*16+h)*64 + d][s'], where
// s' permutes keys within each 64-block by pi(k) = 8*((k>>2)&3) +
// 32*((k>>5)&1) + 4*((k>>4)&1) + (k&3). This makes each flash lane's QK^T
// output registers directly usable as the PV A-fragment (no P LDS roundtrip).
// ---------------------------------------------------------------------------
__global__ __launch_bounds__(256) void transpose_v_k(const ushort* __restrict__ qkv_h,
                                                     ushort* __restrict__ vT_h) {
    __shared__ ushort th[64][68];
    const int st = blockIdx.x, h = blockIdx.y, b = blockIdx.z;
    const int t = threadIdx.x;
    const int s0 = st * 64;
    {
        int s = t >> 2, dc = (t & 3) * 16;
        const size_t src = ((size_t)(b * SEQ + s0 + s)) * 3072 + 2048 + h * 64 + dc;
        *(uint4*)&th[s][dc]     = *(const uint4*)&qkv_h[src];
        *(uint4*)&th[s][dc + 8] = *(const uint4*)&qkv_h[src + 8];
    }
    __syncthreads();
    {
        int d = t >> 2, sc = (t & 3) * 16;
        // pi on k = sc + 4*jj + r: (k>>2)&3 = jj, so k' = 8*jj + c_off + r
        const int c_off = ((sc & 16) ? 4 : 0) + ((sc & 32) ? 32 : 0);
        const size_t dstbase = ((size_t)((b * 16 + h) * 64 + d)) * SEQ + s0;
#pragma unroll
        for (int jj = 0; jj < 4; ++jj) {
            ushort4 v;
            v.x = th[sc + 4 * jj + 0][d];
            v.y = th[sc + 4 * jj + 1][d];
            v.z = th[sc + 4 * jj + 2][d];
            v.w = th[sc + 4 * jj + 3][d];
            *(ushort4*)&vT_h[dstbase + 8 * jj + c_off] = v;
        }
    }
}

// ---------------------------------------------------------------------------
// bf16 MFMA GEMM, pipelined, 1-term (Ah*Bh): C[M,N] = A @ B
// A row-major [.,K] (lda, col offset aoff); B as B^T row-major [N][K].
// 128x128 tile, BK=32, 4 waves (2x2), 4x4 16x16 frags/wave.
// Cooperative staging, double-buffered LDS, counted vmcnt + raw s_barrier.
// T1: XCD-aware bijective block remap (nwg % 8 == 0).
// ---------------------------------------------------------------------------
template <int OUT_SPLIT>
__global__ __launch_bounds__(256) void gemm_k(
    const ushort* __restrict__ Ah, int lda, int aoff,
    const ushort* __restrict__ BhT,
    ushort* __restrict__ Ch, float* __restrict__ Cf,
    int ldc, int coff, int K) {
    __shared__ __align__(16) ushort lds[2][2][4096];   // [buf][0=A,1=B]
    const int t = threadIdx.x;
    const int lane = t & 63, wid = t >> 6;
    const int wm = (wid >> 1) * 64, wn = (wid & 1) * 64;

    // XCD-aware remap (bijective since nwg % 8 == 0)
    const int gx = gridDim.x;
    const int nwg = gx * gridDim.y;
    const int flat = blockIdx.y * gx + blockIdx.x;
    const int swzid = (flat & 7) * (nwg >> 3) + (flat >> 3);
    const int row0 = (swzid / gx) * 128, col0 = (swzid % gx) * 128;

    f32x4 acc[4][4];
#pragma unroll
    for (int i = 0; i < 4; ++i)
#pragma unroll
        for (int j = 0; j < 4; ++j) acc[i][j] = f32x4{0.f, 0.f, 0.f, 0.f};

    const int r_loc = lane >> 2;                       // 0..15
    const int c_src = (lane & 3) ^ ((lane >> 3) & 3);  // pre-swizzled source col
    const int swz = ((lane & 15) >> 1) & 3;
    const int ch = (((lane >> 4) ^ swz) * 8);
    const int rA = wm + (lane & 15);
    const int rB = wn + (lane & 15);

    // each wave stages 4 chunks (1KB each); chunk c -> tile c>>3, rows (c&7)*16+
    auto stage = [&](int buf, int kk) {
#pragma unroll
        for (int ic = 0; ic < 4; ++ic) {
            const int c = wid * 4 + ic;
            const int tile = c >> 3, chi = c & 7;
            const ushort* s = tile ? BhT : Ah;
            const int sr = tile ? col0 : row0;
            const int sl = tile ? K : lda;
            const int so = tile ? 0 : aoff;
            const ushort* gp =
                s + (size_t)(sr + chi * 16 + r_loc) * sl + so + kk + c_src * 8;
            gload_lds16(gp, &lds[buf][tile][chi * 512 + 0]);
        }
    };

    stage(0, 0);
    for (int k0 = 0; k0 < K; k0 += 32) {
        const int cur = (k0 >> 5) & 1;
        if (k0 + 32 < K) {
            stage(cur ^ 1, k0 + 32);   // prefetch next K-tile
            asm volatile("s_waitcnt vmcnt(4)" ::: "memory");
        } else {
            asm volatile("s_waitcnt vmcnt(0)" ::: "memory");
        }
        __builtin_amdgcn_s_barrier();      // cur buffer landed (all waves)
        __builtin_amdgcn_sched_barrier(0);

        short8 ah[4], bh[4];
#pragma unroll
        for (int f = 0; f < 4; ++f) {
            ah[f] = *(const short8*)&lds[cur][0][(rA + f * 16) * 32 + ch];
            bh[f] = *(const short8*)&lds[cur][1][(rB + f * 16) * 32 + ch];
        }
        __builtin_amdgcn_s_setprio(1);
#pragma unroll
        for (int i = 0; i < 4; ++i)
#pragma unroll
            for (int j = 0; j < 4; ++j) acc[i][j] = mfma16(ah[i], bh[j], acc[i][j]);
        __builtin_amdgcn_s_setprio(0);
        asm volatile("s_waitcnt lgkmcnt(0)" ::: "memory");  // reads of cur retired
        __builtin_amdgcn_s_barrier();
        __builtin_amdgcn_sched_barrier(0);
    }
    // epilogue; C/D layout: row=(lane>>4)*4+reg, col=lane&15
#pragma unroll
    for (int i = 0; i < 4; ++i)
#pragma unroll
        for (int j = 0; j < 4; ++j)
#pragma unroll
            for (int r = 0; r < 4; ++r) {
                int row = row0 + wm + i * 16 + (lane >> 4) * 4 + r;
                int col = col0 + wn + j * 16 + (lane & 15);
                float v = acc[i][j][r];
                if (OUT_SPLIT) {
                    Ch[(size_t)row * ldc + coff + col] = f2bf(v);
                } else {
                    Cf[(size_t)row * ldc + coff + col] = v;
                }
            }
}

// ---------------------------------------------------------------------------
// MFMA flash attention, pipelined, all bf16, 8 waves / QBLK=128.
// Q pre-scaled by CSC -> softmax = exp2(s) direct; no max-tracking.
// kt-loop unrolled x2 (static buffer index). XCD-aware flat grid.
// K AND V double-buffered, counted vmcnt(2). P never touches LDS
// (pi-permuted V; QK^T registers pack directly into the PV A-fragment).
// l computed VIA MFMA: lsum = mfma(pa, ones) accumulates P row-sums in the
// SAME (row,lane) layout as o -> no rs adds, no cross-lane reduce, epilogue
// invr = 1/lsum[r] directly. LDS = 32 KB -> all 1024 blocks resident.
// ---------------------------------------------------------------------------
__global__ __launch_bounds__(512) void flash_mfma(
    const ushort* __restrict__ qkv_h, const ushort* __restrict__ vT_h,
    ushort* __restrict__ attn_h) {
    const int id = blockIdx.x;
    const int bh = id & 63, qt = id >> 6;
    const int h = bh & 15, b = bh >> 4;
    const int t = threadIdx.x, lane = t & 63, wid = t >> 6;  // wid 0..7
    const int q = lane & 15, g = lane >> 4;
    const int qs7 = q & 7;

    __shared__ __align__(16) ushort Kb[2][4096];   // 8 KB per buf (64x64)
    __shared__ __align__(16) ushort Vb[2][4096];

    const size_t tokbase = (size_t)b * SEQ;
    const int q0 = qt * 128;
    const int kv_r = lane >> 3;
    const int kv_csrc = (lane & 7) ^ ((lane >> 3) & 7);
    const size_t vbase = ((size_t)(b * 16 + h) * 64) * SEQ;

    // ---- stage Q (128 rows) into Kb[0..1] (16 KB contiguous): 16 chunks
    ushort* KQ = &Kb[0][0];
#pragma unroll
    for (int is = 0; is < 2; ++is) {
        int ci = wid * 2 + is;
        const ushort* gq =
            qkv_h + (tokbase + q0 + ci * 8 + kv_r) * 3072 + h * 64 + kv_csrc * 8;
        gload_lds16(gq, KQ + ci * 512);
    }
    __syncthreads();  // drains vmcnt -> Q landed
    const int ck0 = (g ^ qs7) * 8;
    const int ck1 = ((g + 4) ^ qs7) * 8;
    short8 qh[2];
    {
        const int row = wid * 16 + q;
        qh[0] = *(const short8*)&KQ[row * 64 + ck0];
        qh[1] = *(const short8*)&KQ[row * 64 + ck1];
    }
    __syncthreads();  // frag reads retired before K overwrites

    // hoisted per-lane LDS offsets (kt-invariant)
    const int qck0 = q * 64 + ck0;            // K/V read base, slice 0
    const int qck1 = q * 64 + ck1;            // slice 1

    // all-ones bf16 B-fragment for the l-sum MFMA
    const short one_bf = (short)0x3F80;
    const short8 ones = {one_bf, one_bf, one_bf, one_bf,
                         one_bf, one_bf, one_bf, one_bf};

    auto stage = [&](int buf, int kv0) {
        if (wid < 4) {
            const ushort* gsrc =
                qkv_h + (tokbase + kv0 + wid * 16) * 3072 + 1024 + h * 64;
            ushort* dst = &Kb[buf][wid * 1024];
#pragma unroll
            for (int is = 0; is < 2; ++is)
                gload_lds16(gsrc + (size_t)(is * 8 + kv_r) * 3072 + kv_csrc * 8,
                            dst + is * 512);
        } else {
            const ushort* gsrc = vT_h + vbase + (size_t)((wid - 4) * 16) * SEQ + kv0;
            ushort* dst = &Vb[buf][(wid - 4) * 1024];
#pragma unroll
            for (int is = 0; is < 2; ++is)
                gload_lds16(gsrc + (size_t)(is * 8 + kv_r) * SEQ + kv_csrc * 8,
                            dst + is * 512);
        }
    };

    stage(0, 0);  // 2 loads/wave in flight

    f32x4 lsum = f32x4{0.f, 0.f, 0.f, 0.f};   // P row-sums, same layout as o
    f32x4 o[4];
#pragma unroll
    for (int i = 0; i < 4; ++i) o[i] = f32x4{0.f, 0.f, 0.f, 0.f};

    // per-tile body; cur is a compile-time constant at each call site
    auto body = [&](int cur) {
        const ushort* Kc = &Kb[cur][0];
        const ushort* Vc = &Vb[cur][0];

        // ---- S^T (pre-scaled): lane owns q-row q; s[j][r] = key 16j+4g+r
        f32x4 s[4];
#pragma unroll
        for (int j = 0; j < 4; ++j) s[j] = f32x4{0.f, 0.f, 0.f, 0.f};
        __builtin_amdgcn_s_setprio(1);
#pragma unroll
        for (int j = 0; j < 4; ++j) {
            short8 kh0 = *(const short8*)&Kc[j * 1024 + qck0];
            s[j] = mfma16(kh0, qh[0], s[j]);
            short8 kh1 = *(const short8*)&Kc[j * 1024 + qck1];
            s[j] = mfma16(kh1, qh[1], s[j]);
        }
        __builtin_amdgcn_s_setprio(0);

        // ---- softmax: P = exp2(s); pack straight into PV A-fragments.
        // pi-permuted V makes register order == fragment order:
        // pa[j>>1] elements (j&1)*4+r  <->  key 16j+4g+r.
        short8 pa[2];
#pragma unroll
        for (int j = 0; j < 4; ++j) {
            float p0 = __builtin_exp2f(s[j][0]);
            float p1 = __builtin_exp2f(s[j][1]);
            float p2 = __builtin_exp2f(s[j][2]);
            float p3 = __builtin_exp2f(s[j][3]);
            pa[j >> 1][(j & 1) * 4 + 0] = (short)f2bf(p0);
            pa[j >> 1][(j & 1) * 4 + 1] = (short)f2bf(p1);
            pa[j >> 1][(j & 1) * 4 + 2] = (short)f2bf(p2);
            pa[j >> 1][(j & 1) * 4 + 3] = (short)f2bf(p3);
        }

        // ---- O += P V ; l += P 1  (both on the MFMA pipe)
        __builtin_amdgcn_s_setprio(1);
#pragma unroll
        for (int ks = 0; ks < 2; ++ks) {
            lsum = mfma16(pa[ks], ones, lsum);
#pragma unroll
            for (int jp = 0; jp < 4; ++jp) {
                short8 vh = *(const short8*)&Vc[jp * 1024 + (ks ? qck1 : qck0)];
                o[jp] = mfma16(pa[ks], vh, o[jp]);
            }
        }
        __builtin_amdgcn_s_setprio(0);

        asm volatile("s_waitcnt lgkmcnt(0)" ::: "memory");  // cur reads retired
        __builtin_amdgcn_s_barrier();        // all waves done with cur
        __builtin_amdgcn_sched_barrier(0);
    };

    for (int kt2 = 0; kt2 < SEQ / 128; ++kt2) {
        // ---- sub 0: tile 2*kt2 in buf 0 (prefetch 2*kt2+1 -> buf 1)
        stage(1, (kt2 * 2 + 1) * 64);
        asm volatile("s_waitcnt vmcnt(2)" ::: "memory");
        __builtin_amdgcn_s_barrier();
        __builtin_amdgcn_sched_barrier(0);
        body(0);
        // ---- sub 1: tile 2*kt2+1 in buf 1 (prefetch 2*kt2+2 -> buf 0)
        if (kt2 < SEQ / 128 - 1) {
            stage(0, (kt2 * 2 + 2) * 64);
            asm volatile("s_waitcnt vmcnt(2)" ::: "memory");
        } else {
            asm volatile("s_waitcnt vmcnt(0)" ::: "memory");
        }
        __builtin_amdgcn_s_barrier();
        __builtin_amdgcn_sched_barrier(0);
        body(1);
    }

    // ---- epilogue: normalize (lsum[r] = l for tok row 4g+r), write bf16
#pragma unroll
    for (int r = 0; r < 4; ++r) {
        float invr = 1.f / lsum[r];
        int tok = q0 + wid * 16 + g * 4 + r;
        size_t rowb = (tokbase + tok) * 3072;
#pragma unroll
        for (int jp = 0; jp < 4; ++jp) {
            int col = h * 64 + jp * 16 + q;
            attn_h[rowb + col] = f2bf(o[jp][r] * invr);
        }
    }
}

// ---------------------------------------------------------------------------

extern "C" void kernel_launch(void* const* d_in, const int* in_sizes, int n_in,
                              void* d_out, int out_size, void* d_ws, size_t ws_size,
                              hipStream_t stream) {
    const float* x      = (const float*)d_in[0];  // [B,S,D]
    const float* W_attn = (const float*)d_in[1];  // [D,3D]
    const float* W_proj = (const float*)d_in[2];  // [D,D]

    const int M = BATCH * SEQ;  // 8192

    // ws layout (~72 MiB)
    ushort* qkv_h = (ushort*)d_ws;                    // [8192][3072]  48 MB
    ushort* WaT   = qkv_h + (size_t)M * 3072;         // [3072][1024]   6 MB
    ushort* WpT   = WaT + (size_t)3072 * 1024;        // [1024][1024]   2 MB
    ushort* vT_h  = WpT + (size_t)1024 * 1024;        // [4096][2048]  16 MB

    // d_out doubles as scratch for xh, then holds the final fp32 output
    ushort* xh = (ushort*)d_out;                      // [8192][1024]

    // 1) fused prep: x->bf16, W_attn^T (Q-cols CSC-scaled), W_proj^T
    prep_k<<<dim3(6144), 256, 0, stream>>>(x, W_attn, W_proj, xh, WaT, WpT);
    // 2) qkv = xh @ Wh_attn (pure bf16, pipelined, XCD-swizzled grid)
    gemm_k<1><<<dim3(24, 64), 256, 0, stream>>>(xh, 1024, 0, WaT,
                                                qkv_h, nullptr, 3072, 0, 1024);
    // 3) v columns -> vT (pi-permuted keys, d_ws)
    transpose_v_k<<<dim3(32, 16, 4), 256, 0, stream>>>(qkv_h, vT_h);
    // 4) flash attention (8-wave, QBLK=128, XCD-aware flat grid, 32KB LDS)
    flash_mfma<<<dim3(1024), 512, 0, stream>>>(qkv_h, vT_h, qkv_h + 2048);
    // 5) out = attn @ W_proj (fp32 out, pure bf16, pipelined, XCD-swizzled)
    gemm_k<0><<<dim3(8, 64), 256, 0, stream>>>(qkv_h, 3072, 2048, WpT,
                                               nullptr, (float*)d_out, 1024, 0,
                                               1024);
}